// Round 6
// baseline (288.350 us; speedup 1.0000x reference)
//
#include <hip/hip_runtime.h>

#define N_NODES 100000
#define N_EDGES 1600000
#define B_GRAPHS 64
#define BN_EPS 1e-5

#define NBUCK 256
#define BUCK_NODES 392   // 256*392 = 100352 >= N_NODES; 392 < 512 -> 9-bit local id
#define BUCK_CAP 8192    // fixed per-bucket capacity; mean 6250, sigma 79 -> +24 sigma margin
#define PART_CHUNK 4096
#define NB_PART 391      // cdiv(N_EDGES, PART_CHUNK)

#define QSCALE 2048.0f            // 2^11 int16 fixed-point scale
#define QINV   4.8828125e-4f      // 2^-11

typedef _Float16 half4_t __attribute__((ext_vector_type(4)));
typedef short short4_t __attribute__((ext_vector_type(4)));
typedef int intv2 __attribute__((ext_vector_type(2)));
typedef int intv4 __attribute__((ext_vector_type(4)));
typedef float floatv4 __attribute__((ext_vector_type(4)));

static inline int cdiv(long long a, int b) { return (int)((a + b - 1) / b); }

__device__ __forceinline__ short q16(float v) {
    int q = __float2int_rn(v * QSCALE);
    q = q > 32767 ? 32767 : (q < -32768 ? -32768 : q);
    return (short)q;
}

// ---------------- phase 1: partition edges into fixed-capacity buckets ----------------
// Per-block LDS histogram -> one global atomicAdd per (block,bucket) reserves slots
// directly (no global hist/scan pass needed: fixed BUCK_CAP layout).
// Edge order nondeterministic; downstream sums are order-INDEPENDENT (int accumulation).
__global__ void part_scatter_kernel(const int* __restrict__ row, const int* __restrict__ col,
                                    int* __restrict__ bucket_cnt, unsigned* __restrict__ part_edges) {
    __shared__ int h[NBUCK];
    __shared__ int base_s[NBUCK];
    __shared__ int cur_s[NBUCK];
    long long ebase = (long long)blockIdx.x * PART_CHUNK;
    int n = (N_EDGES - ebase < PART_CHUNK) ? (int)(N_EDGES - ebase) : PART_CHUNK;
    for (int i = threadIdx.x; i < NBUCK; i += 256) h[i] = 0;
    __syncthreads();
    for (int i = threadIdx.x; i < n; i += 256)
        atomicAdd(&h[col[ebase + i] / BUCK_NODES], 1);
    __syncthreads();
    for (int i = threadIdx.x; i < NBUCK; i += 256) {
        int c = h[i];
        base_s[i] = c ? atomicAdd(&bucket_cnt[i], c) : 0;
        cur_s[i] = 0;
    }
    __syncthreads();
    for (int i = threadIdx.x; i < n; i += 256) {
        int r = row[ebase + i], c = col[ebase + i];
        int bkt = c / BUCK_NODES;
        int p = base_s[bkt] + atomicAdd(&cur_s[bkt], 1);
        part_edges[bkt * BUCK_CAP + p] = ((unsigned)r << 9) | (unsigned)(c - bkt * BUCK_NODES);
    }
}

// ---------------- phase 2: per-bucket CSR build + fused scale_x (int16 fixed-point, pad 3->4) ----------------
__global__ void csr_build_kernel(const int* __restrict__ bucket_cnt, const unsigned* __restrict__ part_edges,
                                 int* __restrict__ row_ptr, int* __restrict__ deg,
                                 float* __restrict__ dis, int* __restrict__ sorted_row,
                                 const float* __restrict__ x, short* __restrict__ xs4) {
    __shared__ int hist[BUCK_NODES];  // histogram, then reused as scatter cursors
    __shared__ int tsum[256];
    int b = blockIdx.x;
    int t = threadIdx.x;
    int nbase = b * BUCK_NODES;
    int ebase = b * BUCK_CAP;
    int ne = bucket_cnt[b];
    for (int i = t; i < BUCK_NODES; i += 256) hist[i] = 0;
    __syncthreads();
    for (int i = t; i < ne; i += 256)
        atomicAdd(&hist[part_edges[ebase + i] & 511u], 1);
    __syncthreads();
    int a0 = 0, a1 = 0;
    if (t < BUCK_NODES / 2) { a0 = hist[2 * t]; a1 = hist[2 * t + 1]; tsum[t] = a0 + a1; }
    else tsum[t] = 0;
    __syncthreads();
    for (int off = 1; off < 256; off <<= 1) {
        int u = (t >= off) ? tsum[t - off] : 0;
        __syncthreads();
        tsum[t] += u;
        __syncthreads();
    }
    if (t < BUCK_NODES / 2) {
        int excl = tsum[t] - (a0 + a1);
        hist[2 * t] = excl;
        hist[2 * t + 1] = excl + a0;
        int n0 = nbase + 2 * t, n1 = n0 + 1;
        if (n0 < N_NODES) {
            row_ptr[n0] = ebase + excl;
            deg[n0] = a0;
            dis[n0] = rsqrtf((float)a0 + 1.0f);
        }
        if (n1 < N_NODES) {
            row_ptr[n1] = ebase + excl + a0;
            deg[n1] = a1;
            dis[n1] = rsqrtf((float)a1 + 1.0f);
        }
    }
    __syncthreads();
    for (int i = t; i < ne; i += 256) {
        unsigned e = part_edges[ebase + i];
        int p = atomicAdd(&hist[e & 511u], 1);
        sorted_row[ebase + p] = (int)(e >> 9);
    }
    // fused scale_x (int16 fixed-point) for this bucket's nodes
    for (int i = t; i < BUCK_NODES; i += 256) {
        int n = nbase + i;
        if (n < N_NODES) {
            float d = dis[n];
            short4_t v;
            v.x = q16(x[n * 3 + 0] * d);
            v.y = q16(x[n * 3 + 1] * d);
            v.z = q16(x[n * 3 + 2] * d);
            v.w = 0;
            ((short4_t*)xs4)[n] = v;
        }
    }
}

// ---------------- FUSED: CSR gather (16B int16 vector loads, pure-int accumulation)
//                  -> LDS -> matmul (W in regs, b128 broadcast agg reads) -> fp16 pre
//                  -> BN stats via fp64 global atomicAdd (128 addrs, low contention; no
//                     finalize dispatch needed — fp64 order-wobble ~1e-16, far below tol)
// Activations stored pre-quantized int16; integer accumulation -> order-independent.
template <int WPL> struct VecSel;
template <> struct VecSel<2> { using type = intv2; };
template <> struct VecSel<4> { using type = intv4; };

template <int IN, int OUT, int INSTRIDE, int WPL>
__global__ void gather_mm_kernel(const int* __restrict__ row_ptr, const int* __restrict__ deg,
                                 const int* __restrict__ sorted_row, const float* __restrict__ dis,
                                 const short* __restrict__ hs, const float* __restrict__ W,
                                 const float* __restrict__ b, _Float16* __restrict__ pre,
                                 double* __restrict__ stat_s, double* __restrict__ stat_q) {
    using V = typename VecSel<WPL>::type;
    const int FPL = 2 * WPL;          // int16 features per lane
    const int LPN = INSTRIDE / FPL;   // lanes per node (L1:1, L2:2, L3:4)
    const int NPW = 64 / LPN;         // nodes per wave
    const int NPB = 4 * NPW;          // nodes per block (L1:256, L2:128, L3:64)
    const int UNROLL = 8;
    __shared__ __align__(16) float lds_agg[NPB * INSTRIDE];
    __shared__ double s_s[256];
    __shared__ double s_q[256];
    int tid = threadIdx.x;
    int wv = tid >> 6, lane = tid & 63;
    int jn = wv * NPW + lane / LPN;   // node index within block
    int p = lane % LPN;               // feature-slice index
    int n = blockIdx.x * NPB + jn;
    if (n < N_NODES) {
        int start = row_ptr[n];
        int d = deg[n];
        const int* sr = sorted_row + start;
        const V* hv = (const V*)hs;
        V v = hv[n * LPN + p];        // self-loop term; 32-bit index (fits: N*LPN < 2^31)
        int acc[FPL];
#pragma unroll
        for (int w = 0; w < WPL; w++) {
            acc[2 * w] = (int)(short)v[w];
            acc[2 * w + 1] = v[w] >> 16;
        }
        int j = 0;
        for (; j + UNROLL <= d; j += UNROLL) {
            V a[UNROLL];
#pragma unroll
            for (int u = 0; u < UNROLL; u++) a[u] = hv[sr[j + u] * LPN + p];
#pragma unroll
            for (int u = 0; u < UNROLL; u++) {
#pragma unroll
                for (int w = 0; w < WPL; w++) {
                    acc[2 * w] += (int)(short)a[u][w];
                    acc[2 * w + 1] += a[u][w] >> 16;
                }
            }
        }
        for (; j < d; j++) {
            V a = hv[sr[j] * LPN + p];
#pragma unroll
            for (int w = 0; w < WPL; w++) {
                acc[2 * w] += (int)(short)a[w];
                acc[2 * w + 1] += a[w] >> 16;
            }
        }
        float dn = dis[n] * QINV;
        float* dst = &lds_agg[(jn * LPN + p) * FPL];  // 16B/32B aligned -> ds_write_b128
#pragma unroll
        for (int k = 0; k < FPL; k++) dst[k] = dn * (float)acc[k];
    }
    __syncthreads();

    // ---- matmul + stats phase
    const int NG = 256 / OUT;  // node groups
    int o = tid % OUT;
    int g = tid / OUT;
    float wreg[IN];
#pragma unroll
    for (int k = 0; k < IN; k++) wreg[k] = W[k * OUT + o];
    float bo = b[o];
    double my_s = 0.0, my_q = 0.0;
    for (int j2 = g; j2 < NPB; j2 += NG) {
        int nn = blockIdx.x * NPB + j2;
        if (nn < N_NODES) {
            float acc = bo;
            const floatv4* src = (const floatv4*)&lds_agg[j2 * INSTRIDE];
#pragma unroll
            for (int q = 0; q < INSTRIDE / 4; q++) {
                floatv4 vq = src[q];
#pragma unroll
                for (int c = 0; c < 4; c++) {
                    if (4 * q + c < IN) acc += vq[c] * wreg[4 * q + c];
                }
            }
            _Float16 hq = (_Float16)acc;
            pre[nn * OUT + o] = hq;
            float fq = (float)hq;  // stats on quantized values
            my_s += (double)fq;
            my_q += (double)fq * (double)fq;
        }
    }
    s_s[tid] = my_s;
    s_q[tid] = my_q;
    __syncthreads();
    if (tid < OUT) {
        double ts = 0.0, tq = 0.0;
        for (int k = tid; k < 256; k += OUT) { ts += s_s[k]; tq += s_q[k]; }
        atomicAdd(&stat_s[tid], ts);
        atomicAdd(&stat_q[tid], tq);
    }
}

// ---------------- BN apply + ReLU + dis pre-scale; fp16 in, INT16 fixed-point out ----------------
// Stats finalize fused as a per-block prologue (F sqrts/block — negligible).
template <int F>
__global__ void bn_relu_kernel(const _Float16* __restrict__ pre, const double* __restrict__ stat_s,
                               const double* __restrict__ stat_q, const float* __restrict__ g,
                               const float* __restrict__ be, const float* __restrict__ dis,
                               short* __restrict__ out) {
    const int GP = F / 4;  // quads per node
    __shared__ float As[F], Bs[F];
    int tt = threadIdx.x;
    if (tt < F) {
        double mean = stat_s[tt] / (double)N_NODES;
        double var = stat_q[tt] / (double)N_NODES - mean * mean;
        float m = (float)mean;
        float r = (float)(1.0 / sqrt(var + BN_EPS));
        float A = r * g[tt];
        As[tt] = A;
        Bs[tt] = be[tt] - m * A;
    }
    __syncthreads();
    int t = blockIdx.x * blockDim.x + tt;
    const int total = N_NODES * GP;
    if (t >= total) return;
    int gi = t % GP;
    int f0 = gi * 4;
    half4_t v = ((const half4_t*)pre)[t];
    float d = dis[t / GP];
    short4_t o;
#pragma unroll
    for (int k = 0; k < 4; k++) {
        int f = f0 + k;
        float y = fmaf((float)v[k], As[f], Bs[f]);
        y = y > 0.f ? y : 0.f;
        o[k] = q16(y * d);
    }
    ((short4_t*)out)[t] = o;
}

// ---------------- mean pool with FUSED BN3-finalize+BN3+ReLU (reads fp16 PRE directly) ----------------
#define POOL_CHUNK 32
__global__ void pool_kernel(const _Float16* __restrict__ pre, const int* __restrict__ batch,
                            const double* __restrict__ stat_s, const double* __restrict__ stat_q,
                            const float* __restrict__ g, const float* __restrict__ be,
                            float* __restrict__ pooled, float* __restrict__ cnt) {
    int wave = (blockIdx.x * blockDim.x + threadIdx.x) >> 6;
    int lane = threadIdx.x & 63;  // feature index
    int start = wave * POOL_CHUNK;
    if (start >= N_NODES) return;
    int end = start + POOL_CHUNK;
    if (end > N_NODES) end = N_NODES;
    double mean = stat_s[lane] / (double)N_NODES;
    double var = stat_q[lane] / (double)N_NODES - mean * mean;
    float A = (float)(1.0 / sqrt(var + BN_EPS)) * g[lane];
    float B = be[lane] - (float)mean * A;
    int cur = batch[start];  // wave-uniform -> scalar load
    float acc = 0.f;
    float c = 0.f;
    int i = start;
    for (; i + 4 <= end; i += 4) {
        int b0 = batch[i], b1 = batch[i + 1], b2 = batch[i + 2], b3 = batch[i + 3];
        float v0 = fmaxf(0.f, fmaf((float)pre[(long long)i * 64 + lane], A, B));
        float v1 = fmaxf(0.f, fmaf((float)pre[(long long)(i + 1) * 64 + lane], A, B));
        float v2 = fmaxf(0.f, fmaf((float)pre[(long long)(i + 2) * 64 + lane], A, B));
        float v3 = fmaxf(0.f, fmaf((float)pre[(long long)(i + 3) * 64 + lane], A, B));
        if (b0 != cur) { atomicAdd(&pooled[cur * 64 + lane], acc); if (lane == 0) atomicAdd(&cnt[cur], c); acc = 0.f; c = 0.f; cur = b0; }
        acc += v0; c += 1.f;
        if (b1 != cur) { atomicAdd(&pooled[cur * 64 + lane], acc); if (lane == 0) atomicAdd(&cnt[cur], c); acc = 0.f; c = 0.f; cur = b1; }
        acc += v1; c += 1.f;
        if (b2 != cur) { atomicAdd(&pooled[cur * 64 + lane], acc); if (lane == 0) atomicAdd(&cnt[cur], c); acc = 0.f; c = 0.f; cur = b2; }
        acc += v2; c += 1.f;
        if (b3 != cur) { atomicAdd(&pooled[cur * 64 + lane], acc); if (lane == 0) atomicAdd(&cnt[cur], c); acc = 0.f; c = 0.f; cur = b3; }
        acc += v3; c += 1.f;
    }
    for (; i < end; i++) {
        int b = batch[i];
        if (b != cur) { atomicAdd(&pooled[cur * 64 + lane], acc); if (lane == 0) atomicAdd(&cnt[cur], c); acc = 0.f; c = 0.f; cur = b; }
        acc += fmaxf(0.f, fmaf((float)pre[(long long)i * 64 + lane], A, B)); c += 1.f;
    }
    atomicAdd(&pooled[cur * 64 + lane], acc);
    if (lane == 0) atomicAdd(&cnt[cur], c);
}

// ---------------- final linear ----------------
__global__ void final_kernel(const float* __restrict__ pooled, const float* __restrict__ cnt,
                             const float* __restrict__ fcW, const float* __restrict__ fcb,
                             float* __restrict__ out) {
    int t = blockIdx.x * blockDim.x + threadIdx.x;
    if (t >= B_GRAPHS * 10) return;
    int b = t / 10, j = t % 10;
    float inv = 1.0f / fmaxf(cnt[b], 1.0f);
    float acc = fcb[j];
#pragma unroll
    for (int f = 0; f < 64; f++) acc += pooled[b * 64 + f] * inv * fcW[f * 10 + j];
    out[t] = acc;
}

extern "C" void kernel_launch(void* const* d_in, const int* in_sizes, int n_in,
                              void* d_out, int out_size, void* d_ws, size_t ws_size,
                              hipStream_t stream) {
    const float* x  = (const float*)d_in[0];
    const int* ei   = (const int*)d_in[1];
    const int* batch= (const int*)d_in[2];
    const float* W1 = (const float*)d_in[3];  const float* b1 = (const float*)d_in[4];
    const float* g1 = (const float*)d_in[5];  const float* be1= (const float*)d_in[6];
    const float* W2 = (const float*)d_in[7];  const float* b2 = (const float*)d_in[8];
    const float* g2 = (const float*)d_in[9];  const float* be2= (const float*)d_in[10];
    const float* W3 = (const float*)d_in[11]; const float* b3 = (const float*)d_in[12];
    const float* g3 = (const float*)d_in[13]; const float* be3= (const float*)d_in[14];
    const float* fcW= (const float*)d_in[15]; const float* fcb= (const float*)d_in[16];
    float* out = (float*)d_out;

    const int* row = ei;
    const int* col = ei + N_EDGES;

    // workspace layout — zero region first (one memset): stats, bucket_cnt, pooled, cnt
    char* wp = (char*)d_ws;
    double* stat_s1   = (double*)wp;             wp += 64 * 8;   // only first 16 used
    double* stat_q1   = (double*)wp;             wp += 64 * 8;
    double* stat_s2   = (double*)wp;             wp += 64 * 8;   // only first 32 used
    double* stat_q2   = (double*)wp;             wp += 64 * 8;
    double* stat_s3   = (double*)wp;             wp += 64 * 8;
    double* stat_q3   = (double*)wp;             wp += 64 * 8;
    int*   bucket_cnt = (int*)wp;                wp += NBUCK * 4;
    float* pooled     = (float*)wp;              wp += 64 * 64 * 4;
    float* cnt        = (float*)wp;              wp += 64 * 4;
    const size_t ZERO_BYTES = 6 * 64 * 8 + NBUCK * 4 + 64 * 64 * 4 + 64 * 4;
    float* dis        = (float*)wp;              wp += N_NODES * 4;
    int*   deg_i      = (int*)wp;                wp += N_NODES * 4;
    int*   row_ptr    = (int*)wp;                wp += N_NODES * 4;
    int*   sorted_row = (int*)wp;                wp += (size_t)NBUCK * BUCK_CAP * 4;
    unsigned* part_edges = (unsigned*)wp;        wp += (size_t)NBUCK * BUCK_CAP * 4;
    short* xs4q       = (short*)wp;              wp += (size_t)N_NODES * 4 * 2;
    _Float16* PRE     = (_Float16*)wp;           wp += (size_t)N_NODES * 64 * 2;  // matmul out (fp16)
    short* Hq         = (short*)wp;              wp += (size_t)N_NODES * 32 * 2;  // h1/h2 (int16 fxp, pre-scaled)

    const int BS = 256;

    // ---- one memset for all zero-init state
    hipMemsetAsync(stat_s1, 0, ZERO_BYTES, stream);

    // ---- CSR build: direct fixed-capacity bucket scatter (no global hist/scan pass)
    part_scatter_kernel<<<NB_PART, 256, 0, stream>>>(row, col, bucket_cnt, part_edges);
    csr_build_kernel<<<NBUCK, 256, 0, stream>>>(bucket_cnt, part_edges, row_ptr, deg_i, dis, sorted_row, x, xs4q);

    // ---- layer 1: fused gather(8B/lane)+matmul 3->16 +stats-atomics  (NPB=256 -> 391 blocks)
    const int NB1 = cdiv(N_NODES, 256);
    gather_mm_kernel<3, 16, 4, 2><<<NB1, 256, 0, stream>>>(
        row_ptr, deg_i, sorted_row, dis, xs4q, W1, b1, PRE, stat_s1, stat_q1);
    bn_relu_kernel<16><<<cdiv((long long)N_NODES * 4, BS), BS, 0, stream>>>(
        PRE, stat_s1, stat_q1, g1, be1, dis, Hq);  // Hq = h1 * dis (int16 fxp)

    // ---- layer 2: fused gather(16B/lane)+matmul 16->32 +stats-atomics  (NPB=128 -> 782 blocks)
    const int NB2 = cdiv(N_NODES, 128);
    gather_mm_kernel<16, 32, 16, 4><<<NB2, 256, 0, stream>>>(
        row_ptr, deg_i, sorted_row, dis, Hq, W2, b2, PRE, stat_s2, stat_q2);
    bn_relu_kernel<32><<<cdiv((long long)N_NODES * 8, BS), BS, 0, stream>>>(
        PRE, stat_s2, stat_q2, g2, be2, dis, Hq);  // Hq = h2 * dis (int16 fxp)

    // ---- layer 3: fused gather(16B/lane)+matmul 32->64 +stats-atomics  (NPB=64 -> 1563 blocks)
    const int NB3 = cdiv(N_NODES, 64);
    gather_mm_kernel<32, 64, 32, 4><<<NB3, 256, 0, stream>>>(
        row_ptr, deg_i, sorted_row, dis, Hq, W3, b3, PRE, stat_s3, stat_q3);

    // ---- pool (fused BN3-finalize+BN3+ReLU) + fc
    pool_kernel<<<cdiv((long long)cdiv(N_NODES, POOL_CHUNK) * 64, BS), BS, 0, stream>>>(
        PRE, batch, stat_s3, stat_q3, g3, be3, pooled, cnt);
    final_kernel<<<1, B_GRAPHS * 10, 0, stream>>>(pooled, cnt, fcW, fcb, out);
}

// Round 7
// 258.939 us; speedup vs baseline: 1.1136x; 1.1136x over previous
//
#include <hip/hip_runtime.h>

#define N_NODES 100000
#define N_EDGES 1600000
#define B_GRAPHS 64
#define BN_EPS 1e-5

#define NBUCK 256
#define BUCK_NODES 392   // 256*392 = 100352 >= N_NODES; 392 < 512 -> 9-bit local id
#define BUCK_CAP 8192    // fixed per-bucket capacity; mean 6250, sigma 79 -> +24 sigma margin
#define PART_CHUNK 4096
#define NB_PART 391      // cdiv(N_EDGES, PART_CHUNK)

#define NREP 32          // stats-atomic replicas: 32x fewer same-address collisions (r6 lesson)

#define QSCALE 2048.0f            // 2^11 int16 fixed-point scale
#define QINV   4.8828125e-4f      // 2^-11

typedef _Float16 half4_t __attribute__((ext_vector_type(4)));
typedef short short4_t __attribute__((ext_vector_type(4)));
typedef int intv2 __attribute__((ext_vector_type(2)));
typedef int intv4 __attribute__((ext_vector_type(4)));
typedef float floatv4 __attribute__((ext_vector_type(4)));

static inline int cdiv(long long a, int b) { return (int)((a + b - 1) / b); }

__device__ __forceinline__ short q16(float v) {
    int q = __float2int_rn(v * QSCALE);
    q = q > 32767 ? 32767 : (q < -32768 ? -32768 : q);
    return (short)q;
}

// ---------------- phase 1: partition edges into fixed-capacity buckets ----------------
__global__ void part_scatter_kernel(const int* __restrict__ row, const int* __restrict__ col,
                                    int* __restrict__ bucket_cnt, unsigned* __restrict__ part_edges) {
    __shared__ int h[NBUCK];
    __shared__ int base_s[NBUCK];
    __shared__ int cur_s[NBUCK];
    long long ebase = (long long)blockIdx.x * PART_CHUNK;
    int n = (N_EDGES - ebase < PART_CHUNK) ? (int)(N_EDGES - ebase) : PART_CHUNK;
    for (int i = threadIdx.x; i < NBUCK; i += 256) h[i] = 0;
    __syncthreads();
    for (int i = threadIdx.x; i < n; i += 256)
        atomicAdd(&h[col[ebase + i] / BUCK_NODES], 1);
    __syncthreads();
    for (int i = threadIdx.x; i < NBUCK; i += 256) {
        int c = h[i];
        base_s[i] = c ? atomicAdd(&bucket_cnt[i], c) : 0;
        cur_s[i] = 0;
    }
    __syncthreads();
    for (int i = threadIdx.x; i < n; i += 256) {
        int r = row[ebase + i], c = col[ebase + i];
        int bkt = c / BUCK_NODES;
        int p = base_s[bkt] + atomicAdd(&cur_s[bkt], 1);
        part_edges[bkt * BUCK_CAP + p] = ((unsigned)r << 9) | (unsigned)(c - bkt * BUCK_NODES);
    }
}

// ---------------- phase 2: per-bucket CSR build + fused scale_x (int16 fixed-point, pad 3->4) ----------------
__global__ void csr_build_kernel(const int* __restrict__ bucket_cnt, const unsigned* __restrict__ part_edges,
                                 int* __restrict__ row_ptr, int* __restrict__ deg,
                                 float* __restrict__ dis, int* __restrict__ sorted_row,
                                 const float* __restrict__ x, short* __restrict__ xs4) {
    __shared__ int hist[BUCK_NODES];  // histogram, then reused as scatter cursors
    __shared__ int tsum[256];
    int b = blockIdx.x;
    int t = threadIdx.x;
    int nbase = b * BUCK_NODES;
    int ebase = b * BUCK_CAP;
    int ne = bucket_cnt[b];
    for (int i = t; i < BUCK_NODES; i += 256) hist[i] = 0;
    __syncthreads();
    for (int i = t; i < ne; i += 256)
        atomicAdd(&hist[part_edges[ebase + i] & 511u], 1);
    __syncthreads();
    int a0 = 0, a1 = 0;
    if (t < BUCK_NODES / 2) { a0 = hist[2 * t]; a1 = hist[2 * t + 1]; tsum[t] = a0 + a1; }
    else tsum[t] = 0;
    __syncthreads();
    for (int off = 1; off < 256; off <<= 1) {
        int u = (t >= off) ? tsum[t - off] : 0;
        __syncthreads();
        tsum[t] += u;
        __syncthreads();
    }
    if (t < BUCK_NODES / 2) {
        int excl = tsum[t] - (a0 + a1);
        hist[2 * t] = excl;
        hist[2 * t + 1] = excl + a0;
        int n0 = nbase + 2 * t, n1 = n0 + 1;
        if (n0 < N_NODES) {
            row_ptr[n0] = ebase + excl;
            deg[n0] = a0;
            dis[n0] = rsqrtf((float)a0 + 1.0f);
        }
        if (n1 < N_NODES) {
            row_ptr[n1] = ebase + excl + a0;
            deg[n1] = a1;
            dis[n1] = rsqrtf((float)a1 + 1.0f);
        }
    }
    __syncthreads();
    for (int i = t; i < ne; i += 256) {
        unsigned e = part_edges[ebase + i];
        int p = atomicAdd(&hist[e & 511u], 1);
        sorted_row[ebase + p] = (int)(e >> 9);
    }
    // fused scale_x (int16 fixed-point) for this bucket's nodes
    for (int i = t; i < BUCK_NODES; i += 256) {
        int n = nbase + i;
        if (n < N_NODES) {
            float d = dis[n];
            short4_t v;
            v.x = q16(x[n * 3 + 0] * d);
            v.y = q16(x[n * 3 + 1] * d);
            v.z = q16(x[n * 3 + 2] * d);
            v.w = 0;
            ((short4_t*)xs4)[n] = v;
        }
    }
}

// ---------------- FUSED: CSR gather (16B int16 vector loads, pure-int accumulation)
//                  -> LDS -> matmul (W in regs, b128 broadcast agg reads) -> fp16 pre
//                  -> BN stats via REPLICATED fp64 atomics (rep = blockIdx & 31):
//                     32x fewer same-line collisions than r6's single array (which cost +45us).
template <int WPL> struct VecSel;
template <> struct VecSel<2> { using type = intv2; };
template <> struct VecSel<4> { using type = intv4; };

template <int IN, int OUT, int INSTRIDE, int WPL>
__global__ void gather_mm_kernel(const int* __restrict__ row_ptr, const int* __restrict__ deg,
                                 const int* __restrict__ sorted_row, const float* __restrict__ dis,
                                 const short* __restrict__ hs, const float* __restrict__ W,
                                 const float* __restrict__ b, _Float16* __restrict__ pre,
                                 double* __restrict__ stat_s, double* __restrict__ stat_q) {
    using V = typename VecSel<WPL>::type;
    const int FPL = 2 * WPL;          // int16 features per lane
    const int LPN = INSTRIDE / FPL;   // lanes per node (L1:1, L2:2, L3:4)
    const int NPW = 64 / LPN;         // nodes per wave
    const int NPB = 4 * NPW;          // nodes per block (L1:256, L2:128, L3:64)
    const int UNROLL = 8;
    __shared__ __align__(16) float lds_agg[NPB * INSTRIDE];
    __shared__ double s_s[256];
    __shared__ double s_q[256];
    int tid = threadIdx.x;
    int wv = tid >> 6, lane = tid & 63;
    int jn = wv * NPW + lane / LPN;   // node index within block
    int p = lane % LPN;               // feature-slice index
    int n = blockIdx.x * NPB + jn;
    if (n < N_NODES) {
        int start = row_ptr[n];
        int d = deg[n];
        const int* sr = sorted_row + start;
        const V* hv = (const V*)hs;
        V v = hv[n * LPN + p];        // self-loop term; 32-bit index (fits: N*LPN < 2^31)
        int acc[FPL];
#pragma unroll
        for (int w = 0; w < WPL; w++) {
            acc[2 * w] = (int)(short)v[w];
            acc[2 * w + 1] = v[w] >> 16;
        }
        int j = 0;
        for (; j + UNROLL <= d; j += UNROLL) {
            V a[UNROLL];
#pragma unroll
            for (int u = 0; u < UNROLL; u++) a[u] = hv[sr[j + u] * LPN + p];
#pragma unroll
            for (int u = 0; u < UNROLL; u++) {
#pragma unroll
                for (int w = 0; w < WPL; w++) {
                    acc[2 * w] += (int)(short)a[u][w];
                    acc[2 * w + 1] += a[u][w] >> 16;
                }
            }
        }
        for (; j < d; j++) {
            V a = hv[sr[j] * LPN + p];
#pragma unroll
            for (int w = 0; w < WPL; w++) {
                acc[2 * w] += (int)(short)a[w];
                acc[2 * w + 1] += a[w] >> 16;
            }
        }
        float dn = dis[n] * QINV;
        float* dst = &lds_agg[(jn * LPN + p) * FPL];  // 16B/32B aligned -> ds_write_b128
#pragma unroll
        for (int k = 0; k < FPL; k++) dst[k] = dn * (float)acc[k];
    }
    __syncthreads();

    // ---- matmul + stats phase
    const int NG = 256 / OUT;  // node groups
    int o = tid % OUT;
    int g = tid / OUT;
    float wreg[IN];
#pragma unroll
    for (int k = 0; k < IN; k++) wreg[k] = W[k * OUT + o];
    float bo = b[o];
    double my_s = 0.0, my_q = 0.0;
    for (int j2 = g; j2 < NPB; j2 += NG) {
        int nn = blockIdx.x * NPB + j2;
        if (nn < N_NODES) {
            float acc = bo;
            const floatv4* src = (const floatv4*)&lds_agg[j2 * INSTRIDE];
#pragma unroll
            for (int q = 0; q < INSTRIDE / 4; q++) {
                floatv4 vq = src[q];
#pragma unroll
                for (int c = 0; c < 4; c++) {
                    if (4 * q + c < IN) acc += vq[c] * wreg[4 * q + c];
                }
            }
            _Float16 hq = (_Float16)acc;
            pre[nn * OUT + o] = hq;
            float fq = (float)hq;  // stats on quantized values
            my_s += (double)fq;
            my_q += (double)fq * (double)fq;
        }
    }
    s_s[tid] = my_s;
    s_q[tid] = my_q;
    __syncthreads();
    if (tid < OUT) {
        double ts = 0.0, tq = 0.0;
        for (int k = tid; k < 256; k += OUT) { ts += s_s[k]; tq += s_q[k]; }
        int rep = blockIdx.x & (NREP - 1);
        atomicAdd(&stat_s[rep * 64 + tid], ts);
        atomicAdd(&stat_q[rep * 64 + tid], tq);
    }
}

// ---------------- BN apply + ReLU + dis pre-scale; fp16 in, INT16 fixed-point out ----------------
// Stats finalize fused as a per-block prologue: sum NREP replicas (fixed order).
template <int F>
__global__ void bn_relu_kernel(const _Float16* __restrict__ pre, const double* __restrict__ stat_s,
                               const double* __restrict__ stat_q, const float* __restrict__ g,
                               const float* __restrict__ be, const float* __restrict__ dis,
                               short* __restrict__ out) {
    const int GP = F / 4;  // quads per node
    __shared__ float As[F], Bs[F];
    int tt = threadIdx.x;
    if (tt < F) {
        double ss = 0.0, sq = 0.0;
        for (int r = 0; r < NREP; r++) {
            ss += stat_s[r * 64 + tt];
            sq += stat_q[r * 64 + tt];
        }
        double mean = ss / (double)N_NODES;
        double var = sq / (double)N_NODES - mean * mean;
        float m = (float)mean;
        float rs = (float)(1.0 / sqrt(var + BN_EPS));
        float A = rs * g[tt];
        As[tt] = A;
        Bs[tt] = be[tt] - m * A;
    }
    __syncthreads();
    int t = blockIdx.x * blockDim.x + tt;
    const int total = N_NODES * GP;
    if (t >= total) return;
    int gi = t % GP;
    int f0 = gi * 4;
    half4_t v = ((const half4_t*)pre)[t];
    float d = dis[t / GP];
    short4_t o;
#pragma unroll
    for (int k = 0; k < 4; k++) {
        int f = f0 + k;
        float y = fmaf((float)v[k], As[f], Bs[f]);
        y = y > 0.f ? y : 0.f;
        o[k] = q16(y * d);
    }
    ((short4_t*)out)[t] = o;
}

// ---------------- mean pool with FUSED BN3-finalize+BN3+ReLU (reads fp16 PRE directly) ----------------
#define POOL_CHUNK 32
__global__ void pool_kernel(const _Float16* __restrict__ pre, const int* __restrict__ batch,
                            const double* __restrict__ stat_s, const double* __restrict__ stat_q,
                            const float* __restrict__ g, const float* __restrict__ be,
                            float* __restrict__ pooled, float* __restrict__ cnt) {
    int wave = (blockIdx.x * blockDim.x + threadIdx.x) >> 6;
    int lane = threadIdx.x & 63;  // feature index
    int start = wave * POOL_CHUNK;
    if (start >= N_NODES) return;
    int end = start + POOL_CHUNK;
    if (end > N_NODES) end = N_NODES;
    double ss = 0.0, sq = 0.0;
    for (int r = 0; r < NREP; r++) {
        ss += stat_s[r * 64 + lane];
        sq += stat_q[r * 64 + lane];
    }
    double mean = ss / (double)N_NODES;
    double var = sq / (double)N_NODES - mean * mean;
    float A = (float)(1.0 / sqrt(var + BN_EPS)) * g[lane];
    float B = be[lane] - (float)mean * A;
    int cur = batch[start];  // wave-uniform -> scalar load
    float acc = 0.f;
    float c = 0.f;
    int i = start;
    for (; i + 4 <= end; i += 4) {
        int b0 = batch[i], b1 = batch[i + 1], b2 = batch[i + 2], b3 = batch[i + 3];
        float v0 = fmaxf(0.f, fmaf((float)pre[(long long)i * 64 + lane], A, B));
        float v1 = fmaxf(0.f, fmaf((float)pre[(long long)(i + 1) * 64 + lane], A, B));
        float v2 = fmaxf(0.f, fmaf((float)pre[(long long)(i + 2) * 64 + lane], A, B));
        float v3 = fmaxf(0.f, fmaf((float)pre[(long long)(i + 3) * 64 + lane], A, B));
        if (b0 != cur) { atomicAdd(&pooled[cur * 64 + lane], acc); if (lane == 0) atomicAdd(&cnt[cur], c); acc = 0.f; c = 0.f; cur = b0; }
        acc += v0; c += 1.f;
        if (b1 != cur) { atomicAdd(&pooled[cur * 64 + lane], acc); if (lane == 0) atomicAdd(&cnt[cur], c); acc = 0.f; c = 0.f; cur = b1; }
        acc += v1; c += 1.f;
        if (b2 != cur) { atomicAdd(&pooled[cur * 64 + lane], acc); if (lane == 0) atomicAdd(&cnt[cur], c); acc = 0.f; c = 0.f; cur = b2; }
        acc += v2; c += 1.f;
        if (b3 != cur) { atomicAdd(&pooled[cur * 64 + lane], acc); if (lane == 0) atomicAdd(&cnt[cur], c); acc = 0.f; c = 0.f; cur = b3; }
        acc += v3; c += 1.f;
    }
    for (; i < end; i++) {
        int b = batch[i];
        if (b != cur) { atomicAdd(&pooled[cur * 64 + lane], acc); if (lane == 0) atomicAdd(&cnt[cur], c); acc = 0.f; c = 0.f; cur = b; }
        acc += fmaxf(0.f, fmaf((float)pre[(long long)i * 64 + lane], A, B)); c += 1.f;
    }
    atomicAdd(&pooled[cur * 64 + lane], acc);
    if (lane == 0) atomicAdd(&cnt[cur], c);
}

// ---------------- final linear ----------------
__global__ void final_kernel(const float* __restrict__ pooled, const float* __restrict__ cnt,
                             const float* __restrict__ fcW, const float* __restrict__ fcb,
                             float* __restrict__ out) {
    int t = blockIdx.x * blockDim.x + threadIdx.x;
    if (t >= B_GRAPHS * 10) return;
    int b = t / 10, j = t % 10;
    float inv = 1.0f / fmaxf(cnt[b], 1.0f);
    float acc = fcb[j];
#pragma unroll
    for (int f = 0; f < 64; f++) acc += pooled[b * 64 + f] * inv * fcW[f * 10 + j];
    out[t] = acc;
}

extern "C" void kernel_launch(void* const* d_in, const int* in_sizes, int n_in,
                              void* d_out, int out_size, void* d_ws, size_t ws_size,
                              hipStream_t stream) {
    const float* x  = (const float*)d_in[0];
    const int* ei   = (const int*)d_in[1];
    const int* batch= (const int*)d_in[2];
    const float* W1 = (const float*)d_in[3];  const float* b1 = (const float*)d_in[4];
    const float* g1 = (const float*)d_in[5];  const float* be1= (const float*)d_in[6];
    const float* W2 = (const float*)d_in[7];  const float* b2 = (const float*)d_in[8];
    const float* g2 = (const float*)d_in[9];  const float* be2= (const float*)d_in[10];
    const float* W3 = (const float*)d_in[11]; const float* b3 = (const float*)d_in[12];
    const float* g3 = (const float*)d_in[13]; const float* be3= (const float*)d_in[14];
    const float* fcW= (const float*)d_in[15]; const float* fcb= (const float*)d_in[16];
    float* out = (float*)d_out;

    const int* row = ei;
    const int* col = ei + N_EDGES;

    // workspace layout — zero region first (one memset): replicated stats, bucket_cnt, pooled, cnt
    char* wp = (char*)d_ws;
    double* stat_s1   = (double*)wp;             wp += (size_t)NREP * 64 * 8;
    double* stat_q1   = (double*)wp;             wp += (size_t)NREP * 64 * 8;
    double* stat_s2   = (double*)wp;             wp += (size_t)NREP * 64 * 8;
    double* stat_q2   = (double*)wp;             wp += (size_t)NREP * 64 * 8;
    double* stat_s3   = (double*)wp;             wp += (size_t)NREP * 64 * 8;
    double* stat_q3   = (double*)wp;             wp += (size_t)NREP * 64 * 8;
    int*   bucket_cnt = (int*)wp;                wp += NBUCK * 4;
    float* pooled     = (float*)wp;              wp += 64 * 64 * 4;
    float* cnt        = (float*)wp;              wp += 64 * 4;
    const size_t ZERO_BYTES = 6 * (size_t)NREP * 64 * 8 + NBUCK * 4 + 64 * 64 * 4 + 64 * 4;
    float* dis        = (float*)wp;              wp += N_NODES * 4;
    int*   deg_i      = (int*)wp;                wp += N_NODES * 4;
    int*   row_ptr    = (int*)wp;                wp += N_NODES * 4;
    int*   sorted_row = (int*)wp;                wp += (size_t)NBUCK * BUCK_CAP * 4;
    unsigned* part_edges = (unsigned*)wp;        wp += (size_t)NBUCK * BUCK_CAP * 4;
    short* xs4q       = (short*)wp;              wp += (size_t)N_NODES * 4 * 2;
    _Float16* PRE     = (_Float16*)wp;           wp += (size_t)N_NODES * 64 * 2;  // matmul out (fp16)
    short* Hq         = (short*)wp;              wp += (size_t)N_NODES * 32 * 2;  // h1/h2 (int16 fxp, pre-scaled)

    const int BS = 256;

    // ---- one memset for all zero-init state
    hipMemsetAsync(stat_s1, 0, ZERO_BYTES, stream);

    // ---- CSR build: direct fixed-capacity bucket scatter (no global hist/scan pass)
    part_scatter_kernel<<<NB_PART, 256, 0, stream>>>(row, col, bucket_cnt, part_edges);
    csr_build_kernel<<<NBUCK, 256, 0, stream>>>(bucket_cnt, part_edges, row_ptr, deg_i, dis, sorted_row, x, xs4q);

    // ---- layer 1: fused gather(8B/lane)+matmul 3->16 +replica-stats  (NPB=256 -> 391 blocks)
    const int NB1 = cdiv(N_NODES, 256);
    gather_mm_kernel<3, 16, 4, 2><<<NB1, 256, 0, stream>>>(
        row_ptr, deg_i, sorted_row, dis, xs4q, W1, b1, PRE, stat_s1, stat_q1);
    bn_relu_kernel<16><<<cdiv((long long)N_NODES * 4, BS), BS, 0, stream>>>(
        PRE, stat_s1, stat_q1, g1, be1, dis, Hq);  // Hq = h1 * dis (int16 fxp)

    // ---- layer 2: fused gather(16B/lane)+matmul 16->32 +replica-stats  (NPB=128 -> 782 blocks)
    const int NB2 = cdiv(N_NODES, 128);
    gather_mm_kernel<16, 32, 16, 4><<<NB2, 256, 0, stream>>>(
        row_ptr, deg_i, sorted_row, dis, Hq, W2, b2, PRE, stat_s2, stat_q2);
    bn_relu_kernel<32><<<cdiv((long long)N_NODES * 8, BS), BS, 0, stream>>>(
        PRE, stat_s2, stat_q2, g2, be2, dis, Hq);  // Hq = h2 * dis (int16 fxp)

    // ---- layer 3: fused gather(16B/lane)+matmul 32->64 +replica-stats  (NPB=64 -> 1563 blocks)
    const int NB3 = cdiv(N_NODES, 64);
    gather_mm_kernel<32, 64, 32, 4><<<NB3, 256, 0, stream>>>(
        row_ptr, deg_i, sorted_row, dis, Hq, W3, b3, PRE, stat_s3, stat_q3);

    // ---- pool (fused BN3-finalize+BN3+ReLU) + fc
    pool_kernel<<<cdiv((long long)cdiv(N_NODES, POOL_CHUNK) * 64, BS), BS, 0, stream>>>(
        PRE, batch, stat_s3, stat_q3, g3, be3, pooled, cnt);
    final_kernel<<<1, B_GRAPHS * 10, 0, stream>>>(pooled, cnt, fcW, fcb, out);
}

// Round 9
// 252.464 us; speedup vs baseline: 1.1421x; 1.0256x over previous
//
#include <hip/hip_runtime.h>

#define N_NODES 100000
#define N_EDGES 1600000
#define B_GRAPHS 64
#define BN_EPS 1e-5

#define NBUCK 256
#define BUCK_NODES 392   // 256*392 = 100352 >= N_NODES; 392 < 512 -> 9-bit local id
#define BUCK_CAP 8192    // fixed per-bucket capacity; mean 6250, sigma 79 -> +24 sigma margin
#define PART_CHUNK 4096
#define NB_PART 391      // cdiv(N_EDGES, PART_CHUNK)

#define NREP 32          // stats-atomic replicas: 32x fewer same-address collisions (r6 lesson)

#define QSCALE 2048.0f            // 2^11 int16 fixed-point scale
#define QINV   4.8828125e-4f      // 2^-11

typedef _Float16 half4_t __attribute__((ext_vector_type(4)));
typedef short short4_t __attribute__((ext_vector_type(4)));
typedef int intv2 __attribute__((ext_vector_type(2)));
typedef int intv4 __attribute__((ext_vector_type(4)));
typedef float floatv4 __attribute__((ext_vector_type(4)));

static inline int cdiv(long long a, int b) { return (int)((a + b - 1) / b); }

__device__ __forceinline__ short q16(float v) {
    int q = __float2int_rn(v * QSCALE);
    q = q > 32767 ? 32767 : (q < -32768 ? -32768 : q);
    return (short)q;
}

// ---------------- phase 1: partition edges into fixed-capacity buckets ----------------
__global__ void part_scatter_kernel(const int* __restrict__ row, const int* __restrict__ col,
                                    int* __restrict__ bucket_cnt, unsigned* __restrict__ part_edges) {
    __shared__ int h[NBUCK];
    __shared__ int base_s[NBUCK];
    __shared__ int cur_s[NBUCK];
    long long ebase = (long long)blockIdx.x * PART_CHUNK;
    int n = (N_EDGES - ebase < PART_CHUNK) ? (int)(N_EDGES - ebase) : PART_CHUNK;
    for (int i = threadIdx.x; i < NBUCK; i += 256) h[i] = 0;
    __syncthreads();
    for (int i = threadIdx.x; i < n; i += 256)
        atomicAdd(&h[col[ebase + i] / BUCK_NODES], 1);
    __syncthreads();
    for (int i = threadIdx.x; i < NBUCK; i += 256) {
        int c = h[i];
        base_s[i] = c ? atomicAdd(&bucket_cnt[i], c) : 0;
        cur_s[i] = 0;
    }
    __syncthreads();
    for (int i = threadIdx.x; i < n; i += 256) {
        int r = row[ebase + i], c = col[ebase + i];
        int bkt = c / BUCK_NODES;
        int p = base_s[bkt] + atomicAdd(&cur_s[bkt], 1);
        part_edges[bkt * BUCK_CAP + p] = ((unsigned)r << 9) | (unsigned)(c - bkt * BUCK_NODES);
    }
}

// ---------------- phase 2: per-bucket CSR build + fused scale_x (int16 fixed-point, pad 3->4) ----------------
__global__ void csr_build_kernel(const int* __restrict__ bucket_cnt, const unsigned* __restrict__ part_edges,
                                 int* __restrict__ row_ptr, int* __restrict__ deg,
                                 float* __restrict__ dis, int* __restrict__ sorted_row,
                                 const float* __restrict__ x, short* __restrict__ xs4) {
    __shared__ int hist[BUCK_NODES];  // histogram, then reused as scatter cursors
    __shared__ int tsum[256];
    int b = blockIdx.x;
    int t = threadIdx.x;
    int nbase = b * BUCK_NODES;
    int ebase = b * BUCK_CAP;
    int ne = bucket_cnt[b];
    for (int i = t; i < BUCK_NODES; i += 256) hist[i] = 0;
    __syncthreads();
    for (int i = t; i < ne; i += 256)
        atomicAdd(&hist[part_edges[ebase + i] & 511u], 1);
    __syncthreads();
    int a0 = 0, a1 = 0;
    if (t < BUCK_NODES / 2) { a0 = hist[2 * t]; a1 = hist[2 * t + 1]; tsum[t] = a0 + a1; }
    else tsum[t] = 0;
    __syncthreads();
    for (int off = 1; off < 256; off <<= 1) {
        int u = (t >= off) ? tsum[t - off] : 0;
        __syncthreads();
        tsum[t] += u;
        __syncthreads();
    }
    if (t < BUCK_NODES / 2) {
        int excl = tsum[t] - (a0 + a1);
        hist[2 * t] = excl;
        hist[2 * t + 1] = excl + a0;
        int n0 = nbase + 2 * t, n1 = n0 + 1;
        if (n0 < N_NODES) {
            row_ptr[n0] = ebase + excl;
            deg[n0] = a0;
            dis[n0] = rsqrtf((float)a0 + 1.0f);
        }
        if (n1 < N_NODES) {
            row_ptr[n1] = ebase + excl + a0;
            deg[n1] = a1;
            dis[n1] = rsqrtf((float)a1 + 1.0f);
        }
    }
    __syncthreads();
    for (int i = t; i < ne; i += 256) {
        unsigned e = part_edges[ebase + i];
        int p = atomicAdd(&hist[e & 511u], 1);
        sorted_row[ebase + p] = (int)(e >> 9);
    }
    // fused scale_x (int16 fixed-point) for this bucket's nodes
    for (int i = t; i < BUCK_NODES; i += 256) {
        int n = nbase + i;
        if (n < N_NODES) {
            float d = dis[n];
            short4_t v;
            v.x = q16(x[n * 3 + 0] * d);
            v.y = q16(x[n * 3 + 1] * d);
            v.z = q16(x[n * 3 + 2] * d);
            v.w = 0;
            ((short4_t*)xs4)[n] = v;
        }
    }
}

// ---------------- FUSED: CSR gather, EDGE-PARALLEL (EPN=2: two lanes split each node's
//                  edge list; pure-int halves combined in LDS -> bit-identical to serial).
//                  Halves per-lane serial depth AND doubles grid (occupancy 51% -> ~100%).
//                  -> LDS -> matmul (W in regs, b128 broadcast agg reads) -> fp16 pre
//                  -> BN stats via REPLICATED fp64 atomics (rep = blockIdx & 31).
template <int WPL> struct VecSel;
template <> struct VecSel<2> { using type = intv2; };
template <> struct VecSel<4> { using type = intv4; };

template <int IN, int OUT, int INSTRIDE, int WPL>
__global__ void gather_mm_kernel(const int* __restrict__ row_ptr, const int* __restrict__ deg,
                                 const int* __restrict__ sorted_row, const float* __restrict__ dis,
                                 const short* __restrict__ hs, const float* __restrict__ W,
                                 const float* __restrict__ b, _Float16* __restrict__ pre,
                                 double* __restrict__ stat_s, double* __restrict__ stat_q) {
    using V = typename VecSel<WPL>::type;
    const int FPL = 2 * WPL;          // int16 features per lane
    const int LPN = INSTRIDE / FPL;   // feature slices per node (L1:1, L2:2, L3:4)
    const int LPNE = LPN * 2;         // lanes per node incl. 2 edge-halves
    const int NPW = 64 / LPNE;        // nodes per wave (L1:32, L2:16, L3:8)
    const int NPB = 4 * NPW;          // nodes per block (L1:128, L2:64, L3:32)
    const int UNROLL = 4;             // per-half deg ~8 -> 4-wide main loop covers most
    __shared__ __align__(16) float lds_agg[NPB * INSTRIDE];  // int staging aliases this
    __shared__ double s_s[256];
    __shared__ double s_q[256];
    int tid = threadIdx.x;
    int wv = tid >> 6, lane = tid & 63;
    int jn = wv * NPW + lane / LPNE;  // node index within block
    int sub = lane % LPNE;
    int p = sub % LPN;                // feature-slice index
    int h = sub / LPN;                // edge half
    int n = blockIdx.x * NPB + jn;
    bool active = (n < N_NODES);
    int acc[FPL];
    if (active) {
        int start = row_ptr[n];
        int d = deg[n];
        int jlo = h ? (d >> 1) : 0;
        int jhi = h ? d : (d >> 1);
        const int* sr = sorted_row + start;
        const V* hv = (const V*)hs;
        if (h == 0) {
            V v = hv[n * LPN + p];    // self-loop term (half 0 owns it)
#pragma unroll
            for (int w = 0; w < WPL; w++) {
                acc[2 * w] = (int)(short)v[w];
                acc[2 * w + 1] = v[w] >> 16;
            }
        } else {
#pragma unroll
            for (int k = 0; k < FPL; k++) acc[k] = 0;
        }
        int j = jlo;
        for (; j + UNROLL <= jhi; j += UNROLL) {
            V a[UNROLL];
#pragma unroll
            for (int u = 0; u < UNROLL; u++) a[u] = hv[sr[j + u] * LPN + p];
#pragma unroll
            for (int u = 0; u < UNROLL; u++) {
#pragma unroll
                for (int w = 0; w < WPL; w++) {
                    acc[2 * w] += (int)(short)a[u][w];
                    acc[2 * w + 1] += a[u][w] >> 16;
                }
            }
        }
        for (; j < jhi; j++) {
            V a = hv[sr[j] * LPN + p];
#pragma unroll
            for (int w = 0; w < WPL; w++) {
                acc[2 * w] += (int)(short)a[w];
                acc[2 * w + 1] += a[w] >> 16;
            }
        }
        if (h == 1) {                 // stage half-1 int partials in (aliased) LDS
            int* di = (int*)&lds_agg[(jn * LPN + p) * FPL];
#pragma unroll
            for (int k = 0; k < FPL; k++) di[k] = acc[k];
        }
    }
    __syncthreads();
    if (active && h == 0) {           // combine (pure int add -> bit-identical), scale, store
        float dn = dis[n] * QINV;
        float* dst = &lds_agg[(jn * LPN + p) * FPL];
        int* si = (int*)dst;
        int other[FPL];
#pragma unroll
        for (int k = 0; k < FPL; k++) other[k] = si[k];
#pragma unroll
        for (int k = 0; k < FPL; k++) dst[k] = dn * (float)(acc[k] + other[k]);
    }
    __syncthreads();

    // ---- matmul + stats phase
    const int NG = 256 / OUT;  // node groups
    int o = tid % OUT;
    int g = tid / OUT;
    float wreg[IN];
#pragma unroll
    for (int k = 0; k < IN; k++) wreg[k] = W[k * OUT + o];
    float bo = b[o];
    double my_s = 0.0, my_q = 0.0;
    for (int j2 = g; j2 < NPB; j2 += NG) {
        int nn = blockIdx.x * NPB + j2;
        if (nn < N_NODES) {
            float acc2 = bo;
            const floatv4* src = (const floatv4*)&lds_agg[j2 * INSTRIDE];
#pragma unroll
            for (int q = 0; q < INSTRIDE / 4; q++) {
                floatv4 vq = src[q];
#pragma unroll
                for (int c = 0; c < 4; c++) {
                    if (4 * q + c < IN) acc2 += vq[c] * wreg[4 * q + c];
                }
            }
            _Float16 hq = (_Float16)acc2;
            pre[nn * OUT + o] = hq;
            float fq = (float)hq;  // stats on quantized values
            my_s += (double)fq;
            my_q += (double)fq * (double)fq;
        }
    }
    s_s[tid] = my_s;
    s_q[tid] = my_q;
    __syncthreads();
    if (tid < OUT) {
        double ts = 0.0, tq = 0.0;
        for (int k = tid; k < 256; k += OUT) { ts += s_s[k]; tq += s_q[k]; }
        int rep = blockIdx.x & (NREP - 1);
        atomicAdd(&stat_s[rep * 64 + tid], ts);
        atomicAdd(&stat_q[rep * 64 + tid], tq);
    }
}

// ---------------- BN apply + ReLU + dis pre-scale; fp16 in, INT16 fixed-point out ----------------
// Stats finalize fused as a per-block prologue: sum NREP replicas (fixed order).
template <int F>
__global__ void bn_relu_kernel(const _Float16* __restrict__ pre, const double* __restrict__ stat_s,
                               const double* __restrict__ stat_q, const float* __restrict__ g,
                               const float* __restrict__ be, const float* __restrict__ dis,
                               short* __restrict__ out) {
    const int GP = F / 4;  // quads per node
    __shared__ float As[F], Bs[F];
    int tt = threadIdx.x;
    if (tt < F) {
        double ss = 0.0, sq = 0.0;
        for (int r = 0; r < NREP; r++) {
            ss += stat_s[r * 64 + tt];
            sq += stat_q[r * 64 + tt];
        }
        double mean = ss / (double)N_NODES;
        double var = sq / (double)N_NODES - mean * mean;
        float m = (float)mean;
        float rs = (float)(1.0 / sqrt(var + BN_EPS));
        float A = rs * g[tt];
        As[tt] = A;
        Bs[tt] = be[tt] - m * A;
    }
    __syncthreads();
    int t = blockIdx.x * blockDim.x + tt;
    const int total = N_NODES * GP;
    if (t >= total) return;
    int gi = t % GP;
    int f0 = gi * 4;
    half4_t v = ((const half4_t*)pre)[t];
    float d = dis[t / GP];
    short4_t o;
#pragma unroll
    for (int k = 0; k < 4; k++) {
        int f = f0 + k;
        float y = fmaf((float)v[k], As[f], Bs[f]);
        y = y > 0.f ? y : 0.f;
        o[k] = q16(y * d);
    }
    ((short4_t*)out)[t] = o;
}

// ---------------- mean pool with FUSED BN3-finalize+BN3+ReLU (reads fp16 PRE directly) ----------------
#define POOL_CHUNK 32
__global__ void pool_kernel(const _Float16* __restrict__ pre, const int* __restrict__ batch,
                            const double* __restrict__ stat_s, const double* __restrict__ stat_q,
                            const float* __restrict__ g, const float* __restrict__ be,
                            float* __restrict__ pooled, float* __restrict__ cnt) {
    int wave = (blockIdx.x * blockDim.x + threadIdx.x) >> 6;
    int lane = threadIdx.x & 63;  // feature index
    int start = wave * POOL_CHUNK;
    if (start >= N_NODES) return;
    int end = start + POOL_CHUNK;
    if (end > N_NODES) end = N_NODES;
    double ss = 0.0, sq = 0.0;
    for (int r = 0; r < NREP; r++) {
        ss += stat_s[r * 64 + lane];
        sq += stat_q[r * 64 + lane];
    }
    double mean = ss / (double)N_NODES;
    double var = sq / (double)N_NODES - mean * mean;
    float A = (float)(1.0 / sqrt(var + BN_EPS)) * g[lane];
    float B = be[lane] - (float)mean * A;
    int cur = batch[start];  // wave-uniform -> scalar load
    float acc = 0.f;
    float c = 0.f;
    int i = start;
    for (; i + 4 <= end; i += 4) {
        int b0 = batch[i], b1 = batch[i + 1], b2 = batch[i + 2], b3 = batch[i + 3];
        float v0 = fmaxf(0.f, fmaf((float)pre[(long long)i * 64 + lane], A, B));
        float v1 = fmaxf(0.f, fmaf((float)pre[(long long)(i + 1) * 64 + lane], A, B));
        float v2 = fmaxf(0.f, fmaf((float)pre[(long long)(i + 2) * 64 + lane], A, B));
        float v3 = fmaxf(0.f, fmaf((float)pre[(long long)(i + 3) * 64 + lane], A, B));
        if (b0 != cur) { atomicAdd(&pooled[cur * 64 + lane], acc); if (lane == 0) atomicAdd(&cnt[cur], c); acc = 0.f; c = 0.f; cur = b0; }
        acc += v0; c += 1.f;
        if (b1 != cur) { atomicAdd(&pooled[cur * 64 + lane], acc); if (lane == 0) atomicAdd(&cnt[cur], c); acc = 0.f; c = 0.f; cur = b1; }
        acc += v1; c += 1.f;
        if (b2 != cur) { atomicAdd(&pooled[cur * 64 + lane], acc); if (lane == 0) atomicAdd(&cnt[cur], c); acc = 0.f; c = 0.f; cur = b2; }
        acc += v2; c += 1.f;
        if (b3 != cur) { atomicAdd(&pooled[cur * 64 + lane], acc); if (lane == 0) atomicAdd(&cnt[cur], c); acc = 0.f; c = 0.f; cur = b3; }
        acc += v3; c += 1.f;
    }
    for (; i < end; i++) {
        int b = batch[i];
        if (b != cur) { atomicAdd(&pooled[cur * 64 + lane], acc); if (lane == 0) atomicAdd(&cnt[cur], c); acc = 0.f; c = 0.f; cur = b; }
        acc += fmaxf(0.f, fmaf((float)pre[(long long)i * 64 + lane], A, B)); c += 1.f;
    }
    atomicAdd(&pooled[cur * 64 + lane], acc);
    if (lane == 0) atomicAdd(&cnt[cur], c);
}

// ---------------- final linear ----------------
__global__ void final_kernel(const float* __restrict__ pooled, const float* __restrict__ cnt,
                             const float* __restrict__ fcW, const float* __restrict__ fcb,
                             float* __restrict__ out) {
    int t = blockIdx.x * blockDim.x + threadIdx.x;
    if (t >= B_GRAPHS * 10) return;
    int b = t / 10, j = t % 10;
    float inv = 1.0f / fmaxf(cnt[b], 1.0f);
    float acc = fcb[j];
#pragma unroll
    for (int f = 0; f < 64; f++) acc += pooled[b * 64 + f] * inv * fcW[f * 10 + j];
    out[t] = acc;
}

extern "C" void kernel_launch(void* const* d_in, const int* in_sizes, int n_in,
                              void* d_out, int out_size, void* d_ws, size_t ws_size,
                              hipStream_t stream) {
    const float* x  = (const float*)d_in[0];
    const int* ei   = (const int*)d_in[1];
    const int* batch= (const int*)d_in[2];
    const float* W1 = (const float*)d_in[3];  const float* b1 = (const float*)d_in[4];
    const float* g1 = (const float*)d_in[5];  const float* be1= (const float*)d_in[6];
    const float* W2 = (const float*)d_in[7];  const float* b2 = (const float*)d_in[8];
    const float* g2 = (const float*)d_in[9];  const float* be2= (const float*)d_in[10];
    const float* W3 = (const float*)d_in[11]; const float* b3 = (const float*)d_in[12];
    const float* g3 = (const float*)d_in[13]; const float* be3= (const float*)d_in[14];
    const float* fcW= (const float*)d_in[15]; const float* fcb= (const float*)d_in[16];
    float* out = (float*)d_out;

    const int* row = ei;
    const int* col = ei + N_EDGES;

    // workspace layout — zero region first (one memset): replicated stats, bucket_cnt, pooled, cnt
    char* wp = (char*)d_ws;
    double* stat_s1   = (double*)wp;             wp += (size_t)NREP * 64 * 8;
    double* stat_q1   = (double*)wp;             wp += (size_t)NREP * 64 * 8;
    double* stat_s2   = (double*)wp;             wp += (size_t)NREP * 64 * 8;
    double* stat_q2   = (double*)wp;             wp += (size_t)NREP * 64 * 8;
    double* stat_s3   = (double*)wp;             wp += (size_t)NREP * 64 * 8;
    double* stat_q3   = (double*)wp;             wp += (size_t)NREP * 64 * 8;
    int*   bucket_cnt = (int*)wp;                wp += NBUCK * 4;
    float* pooled     = (float*)wp;              wp += 64 * 64 * 4;
    float* cnt        = (float*)wp;              wp += 64 * 4;
    const size_t ZERO_BYTES = 6 * (size_t)NREP * 64 * 8 + NBUCK * 4 + 64 * 64 * 4 + 64 * 4;
    float* dis        = (float*)wp;              wp += N_NODES * 4;
    int*   deg_i      = (int*)wp;                wp += N_NODES * 4;
    int*   row_ptr    = (int*)wp;                wp += N_NODES * 4;
    int*   sorted_row = (int*)wp;                wp += (size_t)NBUCK * BUCK_CAP * 4;
    unsigned* part_edges = (unsigned*)wp;        wp += (size_t)NBUCK * BUCK_CAP * 4;
    short* xs4q       = (short*)wp;              wp += (size_t)N_NODES * 4 * 2;
    _Float16* PRE     = (_Float16*)wp;           wp += (size_t)N_NODES * 64 * 2;  // matmul out (fp16)
    short* Hq         = (short*)wp;              wp += (size_t)N_NODES * 32 * 2;  // h1/h2 (int16 fxp, pre-scaled)

    const int BS = 256;

    // ---- one memset for all zero-init state
    hipMemsetAsync(stat_s1, 0, ZERO_BYTES, stream);

    // ---- CSR build: direct fixed-capacity bucket scatter (no global hist/scan pass)
    part_scatter_kernel<<<NB_PART, 256, 0, stream>>>(row, col, bucket_cnt, part_edges);
    csr_build_kernel<<<NBUCK, 256, 0, stream>>>(bucket_cnt, part_edges, row_ptr, deg_i, dis, sorted_row, x, xs4q);

    // ---- layer 1: EPN=2 gather(8B/lane)+matmul 3->16 +replica-stats  (NPB=128 -> 782 blocks)
    const int NB1 = cdiv(N_NODES, 128);
    gather_mm_kernel<3, 16, 4, 2><<<NB1, 256, 0, stream>>>(
        row_ptr, deg_i, sorted_row, dis, xs4q, W1, b1, PRE, stat_s1, stat_q1);
    bn_relu_kernel<16><<<cdiv((long long)N_NODES * 4, BS), BS, 0, stream>>>(
        PRE, stat_s1, stat_q1, g1, be1, dis, Hq);  // Hq = h1 * dis (int16 fxp)

    // ---- layer 2: EPN=2 gather(16B/lane)+matmul 16->32 +replica-stats  (NPB=64 -> 1563 blocks)
    const int NB2 = cdiv(N_NODES, 64);
    gather_mm_kernel<16, 32, 16, 4><<<NB2, 256, 0, stream>>>(
        row_ptr, deg_i, sorted_row, dis, Hq, W2, b2, PRE, stat_s2, stat_q2);
    bn_relu_kernel<32><<<cdiv((long long)N_NODES * 8, BS), BS, 0, stream>>>(
        PRE, stat_s2, stat_q2, g2, be2, dis, Hq);  // Hq = h2 * dis (int16 fxp)

    // ---- layer 3: EPN=2 gather(16B/lane)+matmul 32->64 +replica-stats  (NPB=32 -> 3125 blocks)
    const int NB3 = cdiv(N_NODES, 32);
    gather_mm_kernel<32, 64, 32, 4><<<NB3, 256, 0, stream>>>(
        row_ptr, deg_i, sorted_row, dis, Hq, W3, b3, PRE, stat_s3, stat_q3);

    // ---- pool (fused BN3-finalize+BN3+ReLU) + fc
    pool_kernel<<<cdiv((long long)cdiv(N_NODES, POOL_CHUNK) * 64, BS), BS, 0, stream>>>(
        PRE, batch, stat_s3, stat_q3, g3, be3, pooled, cnt);
    final_kernel<<<1, B_GRAPHS * 10, 0, stream>>>(pooled, cnt, fcW, fcb, out);
}

// Round 10
// 244.186 us; speedup vs baseline: 1.1809x; 1.0339x over previous
//
#include <hip/hip_runtime.h>

#define N_NODES 100000
#define N_EDGES 1600000
#define B_GRAPHS 64
#define BN_EPS 1e-5

#define NBUCK 256
#define BUCK_NODES 392   // 256*392 = 100352 >= N_NODES; 392 < 512 -> 9-bit local id
#define BUCK_CAP 8192    // fixed per-bucket capacity; mean 6250, sigma 79 -> +24 sigma margin
#define PART_CHUNK 4096
#define NB_PART 391      // cdiv(N_EDGES, PART_CHUNK)

#define NREP 32          // stats-atomic replicas: 32x fewer same-address collisions (r6 lesson)

#define QSCALE 2048.0f            // 2^11 int16 fixed-point scale
#define QINV   4.8828125e-4f      // 2^-11

typedef _Float16 half4_t __attribute__((ext_vector_type(4)));
typedef short short4_t __attribute__((ext_vector_type(4)));
typedef int intv2 __attribute__((ext_vector_type(2)));
typedef int intv4 __attribute__((ext_vector_type(4)));
typedef float floatv4 __attribute__((ext_vector_type(4)));

static inline int cdiv(long long a, int b) { return (int)((a + b - 1) / b); }

__device__ __forceinline__ short q16(float v) {
    int q = __float2int_rn(v * QSCALE);
    q = q > 32767 ? 32767 : (q < -32768 ? -32768 : q);
    return (short)q;
}

// ---------------- phase 1: partition edges into fixed-capacity buckets (512 thr) ----------------
__global__ void part_scatter_kernel(const int* __restrict__ row, const int* __restrict__ col,
                                    int* __restrict__ bucket_cnt, unsigned* __restrict__ part_edges) {
    __shared__ int h[NBUCK];
    __shared__ int base_s[NBUCK];
    __shared__ int cur_s[NBUCK];
    long long ebase = (long long)blockIdx.x * PART_CHUNK;
    int n = (N_EDGES - ebase < PART_CHUNK) ? (int)(N_EDGES - ebase) : PART_CHUNK;
    for (int i = threadIdx.x; i < NBUCK; i += 512) h[i] = 0;
    __syncthreads();
    for (int i = threadIdx.x; i < n; i += 512)
        atomicAdd(&h[col[ebase + i] / BUCK_NODES], 1);
    __syncthreads();
    for (int i = threadIdx.x; i < NBUCK; i += 512) {
        int c = h[i];
        base_s[i] = c ? atomicAdd(&bucket_cnt[i], c) : 0;
        cur_s[i] = 0;
    }
    __syncthreads();
    for (int i = threadIdx.x; i < n; i += 512) {
        int r = row[ebase + i], c = col[ebase + i];
        int bkt = c / BUCK_NODES;
        int p = base_s[bkt] + atomicAdd(&cur_s[bkt], 1);
        part_edges[bkt * BUCK_CAP + p] = ((unsigned)r << 9) | (unsigned)(c - bkt * BUCK_NODES);
    }
}

// ---------------- phase 2: per-bucket CSR build (512 thr) + fused scale_x ----------------
__global__ void csr_build_kernel(const int* __restrict__ bucket_cnt, const unsigned* __restrict__ part_edges,
                                 int* __restrict__ row_ptr, int* __restrict__ deg,
                                 float* __restrict__ dis, int* __restrict__ sorted_row,
                                 const float* __restrict__ x, short* __restrict__ xs4) {
    __shared__ int hist[BUCK_NODES];  // histogram, then reused as scatter cursors
    __shared__ int tsum[512];
    int b = blockIdx.x;
    int t = threadIdx.x;
    int nbase = b * BUCK_NODES;
    int ebase = b * BUCK_CAP;
    int ne = bucket_cnt[b];
    for (int i = t; i < BUCK_NODES; i += 512) hist[i] = 0;
    __syncthreads();
    for (int i = t; i < ne; i += 512)
        atomicAdd(&hist[part_edges[ebase + i] & 511u], 1);
    __syncthreads();
    int a = (t < BUCK_NODES) ? hist[t] : 0;
    tsum[t] = a;
    __syncthreads();
    for (int off = 1; off < 512; off <<= 1) {
        int u = (t >= off) ? tsum[t - off] : 0;
        __syncthreads();
        tsum[t] += u;
        __syncthreads();
    }
    if (t < BUCK_NODES) {
        int excl = tsum[t] - a;
        hist[t] = excl;  // becomes scatter cursor
        int n0 = nbase + t;
        if (n0 < N_NODES) {
            row_ptr[n0] = ebase + excl;
            deg[n0] = a;
            dis[n0] = rsqrtf((float)a + 1.0f);
        }
    }
    __syncthreads();
    for (int i = t; i < ne; i += 512) {
        unsigned e = part_edges[ebase + i];
        int p = atomicAdd(&hist[e & 511u], 1);
        sorted_row[ebase + p] = (int)(e >> 9);
    }
    // fused scale_x (int16 fixed-point) for this bucket's nodes
    for (int i = t; i < BUCK_NODES; i += 512) {
        int n = nbase + i;
        if (n < N_NODES) {
            float d = dis[n];
            short4_t v;
            v.x = q16(x[n * 3 + 0] * d);
            v.y = q16(x[n * 3 + 1] * d);
            v.z = q16(x[n * 3 + 2] * d);
            v.w = 0;
            ((short4_t*)xs4)[n] = v;
        }
    }
}

// ---------------- FUSED: CSR gather, EDGE-PARALLEL (template EPN lanes split each node's
//                  edge list; pure-int partials combined via LDS int atomicAdd ->
//                  bit-identical under any order). L1/L2: EPN=4, L3: EPN=2.
//                  -> LDS -> matmul (W in regs, b128 broadcast agg reads) -> fp16 pre
//                  -> BN stats via REPLICATED fp64 atomics (rep = blockIdx & 31).
template <int WPL> struct VecSel;
template <> struct VecSel<2> { using type = intv2; };
template <> struct VecSel<4> { using type = intv4; };

template <int IN, int OUT, int INSTRIDE, int WPL, int EPN>
__global__ void gather_mm_kernel(const int* __restrict__ row_ptr, const int* __restrict__ deg,
                                 const int* __restrict__ sorted_row, const float* __restrict__ dis,
                                 const short* __restrict__ hs, const float* __restrict__ W,
                                 const float* __restrict__ b, _Float16* __restrict__ pre,
                                 double* __restrict__ stat_s, double* __restrict__ stat_q) {
    using V = typename VecSel<WPL>::type;
    const int FPL = 2 * WPL;          // int16 features per lane
    const int LPN = INSTRIDE / FPL;   // feature slices per node (L1:1, L2:2, L3:4)
    const int LPNE = LPN * EPN;       // lanes per node incl. edge-chunks
    const int NPW = 64 / LPNE;        // nodes per wave
    const int NPB = 4 * NPW;          // nodes per block (L1:64, L2:32, L3:32)
    const int UNROLL = 4;
    __shared__ __align__(16) float lds_agg[NPB * INSTRIDE];  // int staging aliases this
    __shared__ double s_s[256];
    __shared__ double s_q[256];
    int tid = threadIdx.x;
    int wv = tid >> 6, lane = tid & 63;
    int jn = wv * NPW + lane / LPNE;  // node index within block
    int sub = lane % LPNE;
    int p = sub % LPN;                // feature-slice index
    int h = sub / LPN;                // edge chunk index [0, EPN)
    int n = blockIdx.x * NPB + jn;
    bool active = (n < N_NODES);
    int acc[FPL];
    int* ibuf = (int*)lds_agg;
    int slot = (jn * LPN + p) * FPL;
    if (active) {
        int start = row_ptr[n];
        int d = deg[n];
        int jlo = d * h / EPN;
        int jhi = d * (h + 1) / EPN;
        const int* sr = sorted_row + start;
        const V* hv = (const V*)hs;
        if (h == 0) {
            V v = hv[n * LPN + p];    // self-loop term (chunk 0 owns it)
#pragma unroll
            for (int w = 0; w < WPL; w++) {
                acc[2 * w] = (int)(short)v[w];
                acc[2 * w + 1] = v[w] >> 16;
            }
        } else {
#pragma unroll
            for (int k = 0; k < FPL; k++) acc[k] = 0;
        }
        int j = jlo;
        for (; j + UNROLL <= jhi; j += UNROLL) {
            V a[UNROLL];
#pragma unroll
            for (int u = 0; u < UNROLL; u++) a[u] = hv[sr[j + u] * LPN + p];
#pragma unroll
            for (int u = 0; u < UNROLL; u++) {
#pragma unroll
                for (int w = 0; w < WPL; w++) {
                    acc[2 * w] += (int)(short)a[u][w];
                    acc[2 * w + 1] += a[u][w] >> 16;
                }
            }
        }
        for (; j < jhi; j++) {
            V a = hv[sr[j] * LPN + p];
#pragma unroll
            for (int w = 0; w < WPL; w++) {
                acc[2 * w] += (int)(short)a[w];
                acc[2 * w + 1] += a[w] >> 16;
            }
        }
        if (h == 0) {                 // seed slot with chunk-0 partial (incl. self-loop)
#pragma unroll
            for (int k = 0; k < FPL; k++) ibuf[slot + k] = acc[k];
        }
    }
    __syncthreads();
    if (active && h != 0) {           // int adds commute -> bit-identical any order
#pragma unroll
        for (int k = 0; k < FPL; k++) atomicAdd(&ibuf[slot + k], acc[k]);
    }
    __syncthreads();
    if (active && h == 0) {           // scale and overwrite with float (only owner touches slot)
        float dn = dis[n] * QINV;
        int tot[FPL];
#pragma unroll
        for (int k = 0; k < FPL; k++) tot[k] = ibuf[slot + k];
#pragma unroll
        for (int k = 0; k < FPL; k++) lds_agg[slot + k] = dn * (float)tot[k];
    }
    __syncthreads();

    // ---- matmul + stats phase
    const int NG = 256 / OUT;  // node groups
    int o = tid % OUT;
    int g = tid / OUT;
    float wreg[IN];
#pragma unroll
    for (int k = 0; k < IN; k++) wreg[k] = W[k * OUT + o];
    float bo = b[o];
    double my_s = 0.0, my_q = 0.0;
    for (int j2 = g; j2 < NPB; j2 += NG) {
        int nn = blockIdx.x * NPB + j2;
        if (nn < N_NODES) {
            float acc2 = bo;
            const floatv4* src = (const floatv4*)&lds_agg[j2 * INSTRIDE];
#pragma unroll
            for (int q = 0; q < INSTRIDE / 4; q++) {
                floatv4 vq = src[q];
#pragma unroll
                for (int c = 0; c < 4; c++) {
                    if (4 * q + c < IN) acc2 += vq[c] * wreg[4 * q + c];
                }
            }
            _Float16 hq = (_Float16)acc2;
            pre[nn * OUT + o] = hq;
            float fq = (float)hq;  // stats on quantized values
            my_s += (double)fq;
            my_q += (double)fq * (double)fq;
        }
    }
    s_s[tid] = my_s;
    s_q[tid] = my_q;
    __syncthreads();
    if (tid < OUT) {
        double ts = 0.0, tq = 0.0;
        for (int k = tid; k < 256; k += OUT) { ts += s_s[k]; tq += s_q[k]; }
        int rep = blockIdx.x & (NREP - 1);
        atomicAdd(&stat_s[rep * 64 + tid], ts);
        atomicAdd(&stat_q[rep * 64 + tid], tq);
    }
}

// ---------------- BN apply + ReLU + dis pre-scale; fp16 in, INT16 fixed-point out ----------------
// Stats finalize fused as a per-block prologue: sum NREP replicas (fixed order).
template <int F>
__global__ void bn_relu_kernel(const _Float16* __restrict__ pre, const double* __restrict__ stat_s,
                               const double* __restrict__ stat_q, const float* __restrict__ g,
                               const float* __restrict__ be, const float* __restrict__ dis,
                               short* __restrict__ out) {
    const int GP = F / 4;  // quads per node
    __shared__ float As[F], Bs[F];
    int tt = threadIdx.x;
    if (tt < F) {
        double ss = 0.0, sq = 0.0;
        for (int r = 0; r < NREP; r++) {
            ss += stat_s[r * 64 + tt];
            sq += stat_q[r * 64 + tt];
        }
        double mean = ss / (double)N_NODES;
        double var = sq / (double)N_NODES - mean * mean;
        float m = (float)mean;
        float rs = (float)(1.0 / sqrt(var + BN_EPS));
        float A = rs * g[tt];
        As[tt] = A;
        Bs[tt] = be[tt] - m * A;
    }
    __syncthreads();
    int t = blockIdx.x * blockDim.x + tt;
    const int total = N_NODES * GP;
    if (t >= total) return;
    int gi = t % GP;
    int f0 = gi * 4;
    half4_t v = ((const half4_t*)pre)[t];
    float d = dis[t / GP];
    short4_t o;
#pragma unroll
    for (int k = 0; k < 4; k++) {
        int f = f0 + k;
        float y = fmaf((float)v[k], As[f], Bs[f]);
        y = y > 0.f ? y : 0.f;
        o[k] = q16(y * d);
    }
    ((short4_t*)out)[t] = o;
}

// ---------------- mean pool with FUSED BN3-finalize+BN3+ReLU (reads fp16 PRE directly) ----------------
#define POOL_CHUNK 32
__global__ void pool_kernel(const _Float16* __restrict__ pre, const int* __restrict__ batch,
                            const double* __restrict__ stat_s, const double* __restrict__ stat_q,
                            const float* __restrict__ g, const float* __restrict__ be,
                            float* __restrict__ pooled, float* __restrict__ cnt) {
    int wave = (blockIdx.x * blockDim.x + threadIdx.x) >> 6;
    int lane = threadIdx.x & 63;  // feature index
    int start = wave * POOL_CHUNK;
    if (start >= N_NODES) return;
    int end = start + POOL_CHUNK;
    if (end > N_NODES) end = N_NODES;
    double ss = 0.0, sq = 0.0;
    for (int r = 0; r < NREP; r++) {
        ss += stat_s[r * 64 + lane];
        sq += stat_q[r * 64 + lane];
    }
    double mean = ss / (double)N_NODES;
    double var = sq / (double)N_NODES - mean * mean;
    float A = (float)(1.0 / sqrt(var + BN_EPS)) * g[lane];
    float B = be[lane] - (float)mean * A;
    int cur = batch[start];  // wave-uniform -> scalar load
    float acc = 0.f;
    float c = 0.f;
    int i = start;
    for (; i + 4 <= end; i += 4) {
        int b0 = batch[i], b1 = batch[i + 1], b2 = batch[i + 2], b3 = batch[i + 3];
        float v0 = fmaxf(0.f, fmaf((float)pre[(long long)i * 64 + lane], A, B));
        float v1 = fmaxf(0.f, fmaf((float)pre[(long long)(i + 1) * 64 + lane], A, B));
        float v2 = fmaxf(0.f, fmaf((float)pre[(long long)(i + 2) * 64 + lane], A, B));
        float v3 = fmaxf(0.f, fmaf((float)pre[(long long)(i + 3) * 64 + lane], A, B));
        if (b0 != cur) { atomicAdd(&pooled[cur * 64 + lane], acc); if (lane == 0) atomicAdd(&cnt[cur], c); acc = 0.f; c = 0.f; cur = b0; }
        acc += v0; c += 1.f;
        if (b1 != cur) { atomicAdd(&pooled[cur * 64 + lane], acc); if (lane == 0) atomicAdd(&cnt[cur], c); acc = 0.f; c = 0.f; cur = b1; }
        acc += v1; c += 1.f;
        if (b2 != cur) { atomicAdd(&pooled[cur * 64 + lane], acc); if (lane == 0) atomicAdd(&cnt[cur], c); acc = 0.f; c = 0.f; cur = b2; }
        acc += v2; c += 1.f;
        if (b3 != cur) { atomicAdd(&pooled[cur * 64 + lane], acc); if (lane == 0) atomicAdd(&cnt[cur], c); acc = 0.f; c = 0.f; cur = b3; }
        acc += v3; c += 1.f;
    }
    for (; i < end; i++) {
        int b = batch[i];
        if (b != cur) { atomicAdd(&pooled[cur * 64 + lane], acc); if (lane == 0) atomicAdd(&cnt[cur], c); acc = 0.f; c = 0.f; cur = b; }
        acc += fmaxf(0.f, fmaf((float)pre[(long long)i * 64 + lane], A, B)); c += 1.f;
    }
    atomicAdd(&pooled[cur * 64 + lane], acc);
    if (lane == 0) atomicAdd(&cnt[cur], c);
}

// ---------------- final linear ----------------
__global__ void final_kernel(const float* __restrict__ pooled, const float* __restrict__ cnt,
                             const float* __restrict__ fcW, const float* __restrict__ fcb,
                             float* __restrict__ out) {
    int t = blockIdx.x * blockDim.x + threadIdx.x;
    if (t >= B_GRAPHS * 10) return;
    int b = t / 10, j = t % 10;
    float inv = 1.0f / fmaxf(cnt[b], 1.0f);
    float acc = fcb[j];
#pragma unroll
    for (int f = 0; f < 64; f++) acc += pooled[b * 64 + f] * inv * fcW[f * 10 + j];
    out[t] = acc;
}

extern "C" void kernel_launch(void* const* d_in, const int* in_sizes, int n_in,
                              void* d_out, int out_size, void* d_ws, size_t ws_size,
                              hipStream_t stream) {
    const float* x  = (const float*)d_in[0];
    const int* ei   = (const int*)d_in[1];
    const int* batch= (const int*)d_in[2];
    const float* W1 = (const float*)d_in[3];  const float* b1 = (const float*)d_in[4];
    const float* g1 = (const float*)d_in[5];  const float* be1= (const float*)d_in[6];
    const float* W2 = (const float*)d_in[7];  const float* b2 = (const float*)d_in[8];
    const float* g2 = (const float*)d_in[9];  const float* be2= (const float*)d_in[10];
    const float* W3 = (const float*)d_in[11]; const float* b3 = (const float*)d_in[12];
    const float* g3 = (const float*)d_in[13]; const float* be3= (const float*)d_in[14];
    const float* fcW= (const float*)d_in[15]; const float* fcb= (const float*)d_in[16];
    float* out = (float*)d_out;

    const int* row = ei;
    const int* col = ei + N_EDGES;

    // workspace layout — zero region first (one memset): replicated stats, bucket_cnt, pooled, cnt
    char* wp = (char*)d_ws;
    double* stat_s1   = (double*)wp;             wp += (size_t)NREP * 64 * 8;
    double* stat_q1   = (double*)wp;             wp += (size_t)NREP * 64 * 8;
    double* stat_s2   = (double*)wp;             wp += (size_t)NREP * 64 * 8;
    double* stat_q2   = (double*)wp;             wp += (size_t)NREP * 64 * 8;
    double* stat_s3   = (double*)wp;             wp += (size_t)NREP * 64 * 8;
    double* stat_q3   = (double*)wp;             wp += (size_t)NREP * 64 * 8;
    int*   bucket_cnt = (int*)wp;                wp += NBUCK * 4;
    float* pooled     = (float*)wp;              wp += 64 * 64 * 4;
    float* cnt        = (float*)wp;              wp += 64 * 4;
    const size_t ZERO_BYTES = 6 * (size_t)NREP * 64 * 8 + NBUCK * 4 + 64 * 64 * 4 + 64 * 4;
    float* dis        = (float*)wp;              wp += N_NODES * 4;
    int*   deg_i      = (int*)wp;                wp += N_NODES * 4;
    int*   row_ptr    = (int*)wp;                wp += N_NODES * 4;
    int*   sorted_row = (int*)wp;                wp += (size_t)NBUCK * BUCK_CAP * 4;
    unsigned* part_edges = (unsigned*)wp;        wp += (size_t)NBUCK * BUCK_CAP * 4;
    short* xs4q       = (short*)wp;              wp += (size_t)N_NODES * 4 * 2;
    _Float16* PRE     = (_Float16*)wp;           wp += (size_t)N_NODES * 64 * 2;  // matmul out (fp16)
    short* Hq         = (short*)wp;              wp += (size_t)N_NODES * 32 * 2;  // h1/h2 (int16 fxp, pre-scaled)

    const int BS = 256;

    // ---- one memset for all zero-init state
    hipMemsetAsync(stat_s1, 0, ZERO_BYTES, stream);

    // ---- CSR build: fixed-capacity bucket scatter (512-thread blocks for occupancy)
    part_scatter_kernel<<<NB_PART, 512, 0, stream>>>(row, col, bucket_cnt, part_edges);
    csr_build_kernel<<<NBUCK, 512, 0, stream>>>(bucket_cnt, part_edges, row_ptr, deg_i, dis, sorted_row, x, xs4q);

    // ---- layer 1: EPN=4 gather(8B/lane)+matmul 3->16 +replica-stats  (NPB=64 -> 1563 blocks)
    const int NB1 = cdiv(N_NODES, 64);
    gather_mm_kernel<3, 16, 4, 2, 4><<<NB1, 256, 0, stream>>>(
        row_ptr, deg_i, sorted_row, dis, xs4q, W1, b1, PRE, stat_s1, stat_q1);
    bn_relu_kernel<16><<<cdiv((long long)N_NODES * 4, BS), BS, 0, stream>>>(
        PRE, stat_s1, stat_q1, g1, be1, dis, Hq);  // Hq = h1 * dis (int16 fxp)

    // ---- layer 2: EPN=4 gather(16B/lane)+matmul 16->32 +replica-stats  (NPB=32 -> 3125 blocks)
    const int NB2 = cdiv(N_NODES, 32);
    gather_mm_kernel<16, 32, 16, 4, 4><<<NB2, 256, 0, stream>>>(
        row_ptr, deg_i, sorted_row, dis, Hq, W2, b2, PRE, stat_s2, stat_q2);
    bn_relu_kernel<32><<<cdiv((long long)N_NODES * 8, BS), BS, 0, stream>>>(
        PRE, stat_s2, stat_q2, g2, be2, dis, Hq);  // Hq = h2 * dis (int16 fxp)

    // ---- layer 3: EPN=2 gather(16B/lane)+matmul 32->64 +replica-stats  (NPB=32 -> 3125 blocks)
    const int NB3 = cdiv(N_NODES, 32);
    gather_mm_kernel<32, 64, 32, 4, 2><<<NB3, 256, 0, stream>>>(
        row_ptr, deg_i, sorted_row, dis, Hq, W3, b3, PRE, stat_s3, stat_q3);

    // ---- pool (fused BN3-finalize+BN3+ReLU) + fc
    pool_kernel<<<cdiv((long long)cdiv(N_NODES, POOL_CHUNK) * 64, BS), BS, 0, stream>>>(
        PRE, batch, stat_s3, stat_q3, g3, be3, pooled, cnt);
    final_kernel<<<1, B_GRAPHS * 10, 0, stream>>>(pooled, cnt, fcW, fcb, out);
}